// Round 1
// baseline (260.573 us; speedup 1.0000x reference)
//
#include <hip/hip_runtime.h>
#include <hip/hip_bf16.h>

#define Bdim 2
#define Tdim 4096
#define Ddim 2048
#define Hdim 4
#define DIdim 64
#define NQ 256          // H*DI
#define NCAT 324        // 256 + 64 + 4
#define NPAD 384        // padded N for the projection GEMM
#define Mdim 8192       // B*T

typedef __attribute__((ext_vector_type(8))) short bf16x8;
typedef __attribute__((ext_vector_type(4))) float f32x4;

__device__ __forceinline__ unsigned short f2bf(float f) {
    unsigned int u = __builtin_bit_cast(unsigned int, f);
    u += 0x7fffu + ((u >> 16) & 1u);          // round-to-nearest-even
    return (unsigned short)(u >> 16);
}
__device__ __forceinline__ float bf2f(unsigned short h) {
    unsigned int u = ((unsigned int)h) << 16;
    return __builtin_bit_cast(float, u);
}

// ---------------------------------------------------------------------------
// Kernel A: pack Wq[2048,256] | Wk[2048,64] | Ww[2048,4] -> WcatT[384][2048] bf16
// (transposed so the GEMM's B-tile staging reads contiguous k). Pad cols to 0.
// ---------------------------------------------------------------------------
__global__ __launch_bounds__(256) void pack_w(const float* __restrict__ Wq,
                                              const float* __restrict__ Wk,
                                              const float* __restrict__ Ww,
                                              unsigned short* __restrict__ WcatT) {
    // grid: (NPAD/64, Ddim/64); 64x64 tile transpose via LDS
    const int n0 = blockIdx.x * 64;
    const int d0 = blockIdx.y * 64;
    __shared__ float tile[64][65];
    const int t = threadIdx.x;
#pragma unroll
    for (int i = 0; i < 16; ++i) {
        int flat = i * 256 + t;          // 0..4095
        int r = flat >> 6;               // d offset
        int c = flat & 63;               // n offset
        int n = n0 + c, d = d0 + r;
        float v;
        if (n < NQ)            v = Wq[(size_t)d * NQ + n];
        else if (n < NQ + 64)  v = Wk[(size_t)d * DIdim + (n - NQ)];
        else if (n < NCAT)     v = Ww[(size_t)d * Hdim + (n - NQ - 64)];
        else                   v = 0.0f;
        tile[r][c] = v;
    }
    __syncthreads();
#pragma unroll
    for (int i = 0; i < 16; ++i) {
        int flat = i * 256 + t;
        int nn = flat >> 6;              // n offset
        int dd = flat & 63;              // d offset (fast -> coalesced write)
        WcatT[(size_t)(n0 + nn) * Ddim + d0 + dd] = f2bf(tile[dd][nn]);
    }
}

// ---------------------------------------------------------------------------
// Kernel B: QKW[8192][384] bf16 = bf16(x[8192][2048]) @ WcatT^T
// 128x64 tile, BK=64, 4 waves, mfma_f32_16x16x32_bf16, XOR-swizzled LDS.
// ---------------------------------------------------------------------------
#define BM 128
#define BN 64
#define BK 64

__global__ __launch_bounds__(256) void proj_gemm(const float* __restrict__ x,
                                                 const unsigned short* __restrict__ WcatT,
                                                 unsigned short* __restrict__ QKW) {
    __shared__ __align__(16) unsigned char lds[BM * BK * 2 + BN * BK * 2]; // A:16KB  B:8KB
    const int m0 = blockIdx.y * BM;
    const int n0 = blockIdx.x * BN;
    const int tid = threadIdx.x;
    const int lane = tid & 63;
    const int wave = tid >> 6;

    f32x4 acc[2][4];
#pragma unroll
    for (int ts = 0; ts < 2; ++ts)
#pragma unroll
        for (int ns = 0; ns < 4; ++ns)
            acc[ts][ns] = (f32x4){0.f, 0.f, 0.f, 0.f};

    const int lrow = lane & 15;
    const int kgrp = lane >> 4;          // 0..3

    for (int k0 = 0; k0 < Ddim; k0 += BK) {
        __syncthreads();                 // protect LDS vs previous iter's reads
        // ---- stage A: x[m0..m0+128][k0..k0+64] f32 -> bf16 LDS, swizzled
#pragma unroll
        for (int i = 0; i < 8; ++i) {
            int flat = i * 256 + tid;            // 2048 float4 units
            int r = flat >> 4;                   // row 0..127
            int c4 = flat & 15;                  // float4 col
            const float4 v = *reinterpret_cast<const float4*>(
                &x[(size_t)(m0 + r) * Ddim + k0 + c4 * 4]);
            unsigned int p0 = (unsigned int)f2bf(v.x) | ((unsigned int)f2bf(v.y) << 16);
            unsigned int p1 = (unsigned int)f2bf(v.z) | ((unsigned int)f2bf(v.w) << 16);
            int byte = r * 128 + c4 * 8;
            byte ^= (r & 7) << 4;
            *reinterpret_cast<uint2*>(&lds[byte]) = make_uint2(p0, p1);
        }
        // ---- stage B (transposed source): WcatT[n0..n0+64][k0..k0+64] -> LDS [n][k], swizzled
#pragma unroll
        for (int i = 0; i < 2; ++i) {
            int flat = i * 256 + tid;            // 512 units of 16B
            int n = flat >> 3;                   // 0..63
            int k8 = flat & 7;                   // 16B chunk
            const int4 v = *reinterpret_cast<const int4*>(
                &WcatT[(size_t)(n0 + n) * Ddim + k0 + k8 * 8]);
            int byte = n * 128 + k8 * 16;
            byte ^= (n & 7) << 4;
            *reinterpret_cast<int4*>(&lds[BM * BK * 2 + byte]) = v;
        }
        __syncthreads();
        // ---- compute
#pragma unroll
        for (int ks = 0; ks < 2; ++ks) {
            bf16x8 a[2], bb[4];
#pragma unroll
            for (int ts = 0; ts < 2; ++ts) {
                int r = wave * 32 + ts * 16 + lrow;
                int byte = r * 128 + (ks * 32 + 8 * kgrp) * 2;
                byte ^= (r & 7) << 4;
                a[ts] = *reinterpret_cast<const bf16x8*>(&lds[byte]);
            }
#pragma unroll
            for (int ns = 0; ns < 4; ++ns) {
                int n = ns * 16 + lrow;
                int byte = n * 128 + (ks * 32 + 8 * kgrp) * 2;
                byte ^= (n & 7) << 4;
                bb[ns] = *reinterpret_cast<const bf16x8*>(&lds[BM * BK * 2 + byte]);
            }
#pragma unroll
            for (int ts = 0; ts < 2; ++ts)
#pragma unroll
                for (int ns = 0; ns < 4; ++ns)
                    acc[ts][ns] = __builtin_amdgcn_mfma_f32_16x16x32_bf16(
                        a[ts], bb[ns], acc[ts][ns], 0, 0, 0);
        }
    }
    // ---- epilogue: D col = lane&15, row = (lane>>4)*4 + j
#pragma unroll
    for (int ts = 0; ts < 2; ++ts)
#pragma unroll
        for (int ns = 0; ns < 4; ++ns)
#pragma unroll
            for (int j = 0; j < 4; ++j) {
                int r = m0 + wave * 32 + ts * 16 + kgrp * 4 + j;
                int c = n0 + ns * 16 + lrow;
                QKW[(size_t)r * NPAD + c] = f2bf(acc[ts][ns][j]);
            }
}

// ---------------------------------------------------------------------------
// Kernel C: out[b][t][s] = sum_h w[b,t,h] * relu( Q[b,t,h,:] . K[b,s,:] )
// 128x128 tile per block, 4 waves (32 t-rows each). Operands straight from
// global (QKW is 6.3MB -> L2 resident). No LDS, no barriers.
// ---------------------------------------------------------------------------
__global__ __launch_bounds__(256) void indexer(const unsigned short* __restrict__ QKW,
                                               float* __restrict__ out) {
    const int st = blockIdx.x;           // s tile
    const int tt = blockIdx.y;           // t tile
    const int b  = blockIdx.z;
    const int tid = threadIdx.x;
    const int lane = tid & 63;
    const int wave = tid >> 6;
    const int lrow = lane & 15;
    const int kgrp = lane >> 4;
    const int kcol = 8 * kgrp;           // k offset within 32-wide kstep

    // ---- K fragments: kf[ss][ks], B-operand: col = lane&15 (s-row of K), k contiguous
    bf16x8 kf[8][2];
#pragma unroll
    for (int ss = 0; ss < 8; ++ss)
#pragma unroll
        for (int ks = 0; ks < 2; ++ks) {
            size_t row = (size_t)(b * Tdim + st * 128 + ss * 16 + lrow);
            kf[ss][ks] = *reinterpret_cast<const bf16x8*>(
                &QKW[row * NPAD + NQ + ks * 32 + kcol]);
        }

    // ---- per-head weights for this lane's 8 output rows
    float wreg[2][4][4];                 // [ts][j][h]
#pragma unroll
    for (int ts = 0; ts < 2; ++ts)
#pragma unroll
        for (int j = 0; j < 4; ++j) {
            int t = tt * 128 + wave * 32 + ts * 16 + kgrp * 4 + j;
            const unsigned short* wp = &QKW[(size_t)(b * Tdim + t) * NPAD + NQ + 64];
#pragma unroll
            for (int h = 0; h < Hdim; ++h) wreg[ts][j][h] = bf2f(wp[h]);
        }

    f32x4 oacc[2][8];
#pragma unroll
    for (int ts = 0; ts < 2; ++ts)
#pragma unroll
        for (int ss = 0; ss < 8; ++ss)
            oacc[ts][ss] = (f32x4){0.f, 0.f, 0.f, 0.f};

#pragma unroll
    for (int h = 0; h < Hdim; ++h) {
        bf16x8 qf[2][2];
#pragma unroll
        for (int ts = 0; ts < 2; ++ts)
#pragma unroll
            for (int ks = 0; ks < 2; ++ks) {
                size_t row = (size_t)(b * Tdim + tt * 128 + wave * 32 + ts * 16 + lrow);
                qf[ts][ks] = *reinterpret_cast<const bf16x8*>(
                    &QKW[row * NPAD + h * DIdim + ks * 32 + kcol]);
            }
#pragma unroll
        for (int ss = 0; ss < 8; ++ss) {
            f32x4 d[2];
            d[0] = (f32x4){0.f, 0.f, 0.f, 0.f};
            d[1] = (f32x4){0.f, 0.f, 0.f, 0.f};
#pragma unroll
            for (int ks = 0; ks < 2; ++ks)
#pragma unroll
                for (int ts = 0; ts < 2; ++ts)
                    d[ts] = __builtin_amdgcn_mfma_f32_16x16x32_bf16(
                        qf[ts][ks], kf[ss][ks], d[ts], 0, 0, 0);
#pragma unroll
            for (int ts = 0; ts < 2; ++ts)
#pragma unroll
                for (int j = 0; j < 4; ++j)
                    oacc[ts][ss][j] += wreg[ts][j][h] * fmaxf(d[ts][j], 0.f);
        }
    }

    // ---- store: row = t, col = s
#pragma unroll
    for (int ts = 0; ts < 2; ++ts)
#pragma unroll
        for (int ss = 0; ss < 8; ++ss)
#pragma unroll
            for (int j = 0; j < 4; ++j) {
                int t = tt * 128 + wave * 32 + ts * 16 + kgrp * 4 + j;
                int s = st * 128 + ss * 16 + lrow;
                out[((size_t)b * Tdim + t) * Tdim + s] = oacc[ts][ss][j];
            }
}

// ---------------------------------------------------------------------------
extern "C" void kernel_launch(void* const* d_in, const int* in_sizes, int n_in,
                              void* d_out, int out_size, void* d_ws, size_t ws_size,
                              hipStream_t stream) {
    const float* x  = (const float*)d_in[0];
    const float* Wq = (const float*)d_in[1];
    const float* Wk = (const float*)d_in[2];
    const float* Ww = (const float*)d_in[3];
    float* out = (float*)d_out;

    unsigned short* WcatT = (unsigned short*)d_ws;                       // 384*2048*2 = 1.5MB
    unsigned short* QKW   = (unsigned short*)((char*)d_ws + (size_t)NPAD * Ddim * 2); // 6.3MB

    pack_w<<<dim3(NPAD / 64, Ddim / 64), 256, 0, stream>>>(Wq, Wk, Ww, WcatT);
    proj_gemm<<<dim3(NPAD / BN, Mdim / BM), 256, 0, stream>>>(x, WcatT, QKW);
    indexer<<<dim3(Tdim / 128, Tdim / 128, Bdim), 256, 0, stream>>>(QKW, out);
}